// Round 19
// baseline (424.115 us; speedup 1.0000x reference)
//
#include <hip/hip_runtime.h>
#include <hip/hip_bf16.h>
#include <math.h>

#define DEVI __device__ __forceinline__

typedef __bf16 bf16x8 __attribute__((ext_vector_type(8)));
typedef float f32x4 __attribute__((ext_vector_type(4)));

#define MFMA16(a, b, c) __builtin_amdgcn_mfma_f32_16x16x32_bf16((a), (b), (c), 0, 0, 0)

struct RopeConsts { float inv_freq[32]; };

DEVI float bfbits2f(unsigned int u) { union { unsigned int i; float f; } x; x.i = u << 16; return x.f; }
DEVI unsigned short f2bfbits(float f) {
    __hip_bfloat16 h = __float2bfloat16(f);
    unsigned short u; __builtin_memcpy(&u, &h, 2); return u;
}

DEVI void gl_lds16(const __hip_bfloat16* g, __hip_bfloat16* l) {
    __builtin_amdgcn_global_load_lds((const __attribute__((address_space(1))) void*)g,
                                     (__attribute__((address_space(3))) void*)l, 16, 0, 0);
}

// ---------------- elementwise fp32 -> bf16 ----------------
__global__ void k_cvt_f32_bf16(const float* __restrict__ s, __hip_bfloat16* __restrict__ d, long n) {
    long i = ((long)blockIdx.x * 256 + threadIdx.x) * 4;
    if (i >= n) return;
    float4 f = *(const float4*)(s + i);
    ushort4 o = make_ushort4(f2bfbits(f.x), f2bfbits(f.y), f2bfbits(f.z), f2bfbits(f.w));
    *(ushort4*)((unsigned short*)d + i) = o;
}

// ---------------- batched transpose+convert (wide stores): 5 segments in one launch ----------------
struct TransBatch {
    const float* src[5];
    __hip_bfloat16* dst[5];
    int K[5], N[5], nbx[5];
    int boff[6];
};

__global__ __launch_bounds__(256)
void k_transpose_batch(TransBatch tbp) {
    __shared__ float tile[128][33];
    const int b = blockIdx.x;
    int seg = 0;
    if (b >= tbp.boff[1]) seg = 1;
    if (b >= tbp.boff[2]) seg = 2;
    if (b >= tbp.boff[3]) seg = 3;
    if (b >= tbp.boff[4]) seg = 4;
    const int local = b - tbp.boff[seg];
    const int nbx = tbp.nbx[seg];
    const int K = tbp.K[seg], N = tbp.N[seg];
    const float* __restrict__ src = tbp.src[seg];
    __hip_bfloat16* __restrict__ dst = tbp.dst[seg];
    const int nb = (local % nbx) * 32, kb = (local / nbx) * 128;

    const int tx = threadIdx.x & 31, ty = threadIdx.x >> 5;  // tx: n, ty: k-sub
    #pragma unroll
    for (int r = 0; r < 128; r += 8) {
        int k = kb + r + ty, n = nb + tx;
        tile[r + ty][tx] = (n < N) ? src[(size_t)k * N + n] : 0.0f;
    }
    __syncthreads();
    const int nl = threadIdx.x >> 3;            // 0..31
    const int kq = (threadIdx.x & 7) << 4;      // 0,16,..,112
    unsigned short* drow = (unsigned short*)(dst + (size_t)(nb + nl) * K + kb + kq);
    #pragma unroll
    for (int j4 = 0; j4 < 4; ++j4) {
        ushort4 o;
        o.x = f2bfbits(tile[kq + j4 * 4 + 0][nl]);
        o.y = f2bfbits(tile[kq + j4 * 4 + 1][nl]);
        o.z = f2bfbits(tile[kq + j4 * 4 + 2][nl]);
        o.w = f2bfbits(tile[kq + j4 * 4 + 3][nl]);
        *(ushort4*)(drow + j4 * 4) = o;
    }
}

// ---------------- C store helpers ----------------
DEVI void storeC(float* C, size_t i, float v) { C[i] = v; }
DEVI void storeC(__hip_bfloat16* C, size_t i, float v) { C[i] = __float2bfloat16(v); }

// ---------------- GEMM 128x(64*NI), 8-wave, counted-vmcnt pipeline; C scaled by alpha ----------------
template <int NI, typename CT>
__global__ __launch_bounds__(512, 2)
void k_gemm128w(const __hip_bfloat16* __restrict__ A, int lda,
                const __hip_bfloat16* __restrict__ Bt,
                CT* __restrict__ C, int N, int K, float alpha) {
    extern __shared__ __hip_bfloat16 sm[];
    __hip_bfloat16* As = sm;                    // [2][8192]
    __hip_bfloat16* Bs = sm + 16384;            // [2][NI*4096]
    const int tid = threadIdx.x;
    const int lane = tid & 63, wave = tid >> 6;
    const int wm = wave >> 2, wn = wave & 3;    // 2 x 4 wave grid
    const size_t bm = (size_t)blockIdx.y * 128, bn = (size_t)blockIdx.x * (64 * NI);

    const int srow8 = lane >> 3;
    const int sch = (lane & 7) ^ srow8;         // inverse-swizzled source chunk
    const __hip_bfloat16* Agb = A + (bm + wave * 8 + srow8) * (size_t)lda + (sch << 3);
    const __hip_bfloat16* Bgb = Bt + (bn + wave * 8 + srow8) * (size_t)K + (sch << 3);
    __hip_bfloat16* AsW = As + wave * 512;
    __hip_bfloat16* BsW = Bs + wave * 512;

    auto stage = [&](int buf, int kt) {
        #pragma unroll
        for (int i = 0; i < 2; ++i)
            gl_lds16(Agb + (size_t)i * 64 * lda + kt, AsW + buf * 8192 + i * 4096);
        #pragma unroll
        for (int i = 0; i < NI; ++i)
            gl_lds16(Bgb + (size_t)i * 64 * K + kt, BsW + buf * (NI * 4096) + i * 4096);
    };

    int aoff[4], boff[NI];
    #pragma unroll
    for (int mi = 0; mi < 4; ++mi) {
        int r = wm * 64 + mi * 16 + (lane & 15);
        aoff[mi] = r * 64 + (((lane >> 4) ^ (r & 7)) << 3);
    }
    #pragma unroll
    for (int ni = 0; ni < NI; ++ni) {
        int r = wn * (16 * NI) + ni * 16 + (lane & 15);
        boff[ni] = r * 64 + (((lane >> 4) ^ (r & 7)) << 3);
    }

    f32x4 acc[4][NI] = {};
    const int NT = K >> 6;

    stage(0, 0);
    stage(1, 64);
    asm volatile("s_waitcnt vmcnt(%0)" :: "n"(2 + NI) : "memory");
    __builtin_amdgcn_s_barrier();
    __builtin_amdgcn_sched_barrier(0);

    for (int t = 0; t < NT; ++t) {
        const int b = t & 1;
        const __hip_bfloat16* Ab = As + b * 8192;
        const __hip_bfloat16* Bb = Bs + b * (NI * 4096);
        bf16x8 af[4], bfr[NI];

        // kk = 0
        #pragma unroll
        for (int mi = 0; mi < 4; ++mi) af[mi] = *(const bf16x8*)(Ab + aoff[mi]);
        #pragma unroll
        for (int ni = 0; ni < NI; ++ni) bfr[ni] = *(const bf16x8*)(Bb + boff[ni]);
        __builtin_amdgcn_s_setprio(1);
        #pragma unroll
        for (int mi = 0; mi < 4; ++mi)
            #pragma unroll
            for (int ni = 0; ni < NI; ++ni)
                acc[mi][ni] = MFMA16(af[mi], bfr[ni], acc[mi][ni]);
        __builtin_amdgcn_s_setprio(0);

        // kk = 1
        #pragma unroll
        for (int mi = 0; mi < 4; ++mi) af[mi] = *(const bf16x8*)(Ab + (aoff[mi] ^ 32));
        #pragma unroll
        for (int ni = 0; ni < NI; ++ni) bfr[ni] = *(const bf16x8*)(Bb + (boff[ni] ^ 32));
        __builtin_amdgcn_s_setprio(1);
        #pragma unroll
        for (int mi = 0; mi < 4; ++mi)
            #pragma unroll
            for (int ni = 0; ni < NI; ++ni)
                acc[mi][ni] = MFMA16(af[mi], bfr[ni], acc[mi][ni]);
        __builtin_amdgcn_s_setprio(0);

        __builtin_amdgcn_sched_barrier(0);
        __builtin_amdgcn_s_barrier();
        if (t + 2 < NT) {
            stage(b, (t + 2) << 6);
            asm volatile("s_waitcnt vmcnt(%0)" :: "n"(2 + NI) : "memory");
        } else {
            asm volatile("s_waitcnt vmcnt(0)" ::: "memory");
        }
        __builtin_amdgcn_s_barrier();
        __builtin_amdgcn_sched_barrier(0);
    }

    const int row0 = (int)bm + wm * 64 + ((lane >> 4) << 2);
    const int col0 = (int)bn + wn * (16 * NI) + (lane & 15);
    #pragma unroll
    for (int mi = 0; mi < 4; ++mi)
        #pragma unroll
        for (int ni = 0; ni < NI; ++ni)
            #pragma unroll
            for (int r = 0; r < 4; ++r)
                storeC(C, (size_t)(row0 + mi * 16 + r) * N + (col0 + ni * 16), acc[mi][ni][r] * alpha);
}

// ---------------- GEMM 128x128, 4-wave, counted-vmcnt pipeline, 64KB static LDS ----------------
template <typename CT>
__global__ __launch_bounds__(256, 2)
void k_gemm128p(const __hip_bfloat16* __restrict__ A, int lda,
                const __hip_bfloat16* __restrict__ Bt,
                CT* __restrict__ C, int N, int K, float alpha) {
    __shared__ __hip_bfloat16 As[2 * 8192];   // [2][128][64]
    __shared__ __hip_bfloat16 Bs[2 * 8192];
    const int tid = threadIdx.x;
    const int lane = tid & 63, wave = tid >> 6;
    const int wm = wave >> 1, wn = wave & 1;           // 2 x 2 wave grid
    const size_t bm = (size_t)blockIdx.y * 128, bn = (size_t)blockIdx.x * 128;

    const int srow8 = lane >> 3;
    const int sch = (lane & 7) ^ srow8;
    const __hip_bfloat16* Agb = A + (bm + wave * 8 + srow8) * (size_t)lda + (sch << 3);
    const __hip_bfloat16* Bgb = Bt + (bn + wave * 8 + srow8) * (size_t)K + (sch << 3);
    __hip_bfloat16* AsW = As + wave * 512;
    __hip_bfloat16* BsW = Bs + wave * 512;

    auto stage = [&](int buf, int kt) {
        #pragma unroll
        for (int i = 0; i < 4; ++i)
            gl_lds16(Agb + (size_t)i * 32 * lda + kt, AsW + buf * 8192 + i * 2048);
        #pragma unroll
        for (int i = 0; i < 4; ++i)
            gl_lds16(Bgb + (size_t)i * 32 * K + kt, BsW + buf * 8192 + i * 2048);
    };

    int aoff[4], boff[4];
    #pragma unroll
    for (int mi = 0; mi < 4; ++mi) {
        int r = wm * 64 + mi * 16 + (lane & 15);
        aoff[mi] = r * 64 + (((lane >> 4) ^ (r & 7)) << 3);
    }
    #pragma unroll
    for (int ni = 0; ni < 4; ++ni) {
        int r = wn * 64 + ni * 16 + (lane & 15);
        boff[ni] = r * 64 + (((lane >> 4) ^ (r & 7)) << 3);
    }

    f32x4 acc[4][4] = {};
    const int NT = K >> 6;

    stage(0, 0);
    stage(1, 64);
    asm volatile("s_waitcnt vmcnt(8)" ::: "memory");
    __builtin_amdgcn_s_barrier();
    __builtin_amdgcn_sched_barrier(0);

    for (int t = 0; t < NT; ++t) {
        const int b = t & 1;
        const __hip_bfloat16* Ab = As + b * 8192;
        const __hip_bfloat16* Bb = Bs + b * 8192;
        bf16x8 af[4], bfr[4];

        #pragma unroll
        for (int mi = 0; mi < 4; ++mi) af[mi] = *(const bf16x8*)(Ab + aoff[mi]);
        #pragma unroll
        for (int ni = 0; ni < 4; ++ni) bfr[ni] = *(const bf16x8*)(Bb + boff[ni]);
        __builtin_amdgcn_s_setprio(1);
        #pragma unroll
        for (int mi = 0; mi < 4; ++mi)
            #pragma unroll
            for (int ni = 0; ni < 4; ++ni)
                acc[mi][ni] = MFMA16(af[mi], bfr[ni], acc[mi][ni]);
        __builtin_amdgcn_s_setprio(0);

        #pragma unroll
        for (int mi = 0; mi < 4; ++mi) af[mi] = *(const bf16x8*)(Ab + (aoff[mi] ^ 32));
        #pragma unroll
        for (int ni = 0; ni < 4; ++ni) bfr[ni] = *(const bf16x8*)(Bb + (boff[ni] ^ 32));
        __builtin_amdgcn_s_setprio(1);
        #pragma unroll
        for (int mi = 0; mi < 4; ++mi)
            #pragma unroll
            for (int ni = 0; ni < 4; ++ni)
                acc[mi][ni] = MFMA16(af[mi], bfr[ni], acc[mi][ni]);
        __builtin_amdgcn_s_setprio(0);

        __builtin_amdgcn_sched_barrier(0);
        __builtin_amdgcn_s_barrier();
        if (t + 2 < NT) {
            stage(b, (t + 2) << 6);
            asm volatile("s_waitcnt vmcnt(8)" ::: "memory");
        } else {
            asm volatile("s_waitcnt vmcnt(0)" ::: "memory");
        }
        __builtin_amdgcn_s_barrier();
        __builtin_amdgcn_sched_barrier(0);
    }

    const int row0 = (int)bm + wm * 64 + ((lane >> 4) << 2);
    const int col0 = (int)bn + wn * 64 + (lane & 15);
    #pragma unroll
    for (int mi = 0; mi < 4; ++mi)
        #pragma unroll
        for (int ni = 0; ni < 4; ++ni)
            #pragma unroll
            for (int r = 0; r < 4; ++r)
                storeC(C, (size_t)(row0 + mi * 16 + r) * N + (col0 + ni * 16), acc[mi][ni][r] * alpha);
}

// ---------------- GEMM 256x256 (8-wave, counted-vmcnt deep pipeline) ----------------
template <typename CT>
__global__ __launch_bounds__(512, 2)
void k_gemm256(const __hip_bfloat16* __restrict__ A, int lda,
               const __hip_bfloat16* __restrict__ Bt,
               CT* __restrict__ C, int N, int K) {
    extern __shared__ __hip_bfloat16 sm[];
    __hip_bfloat16* As = sm;            // [2][16384]
    __hip_bfloat16* Bs = sm + 32768;    // [2][16384]
    const int tid = threadIdx.x;
    const int lane = tid & 63, wave = tid >> 6;
    const int wm = wave >> 2, wn = wave & 3;
    const size_t bm = (size_t)blockIdx.y * 256, bn = (size_t)blockIdx.x * 256;

    const int srow8 = lane >> 3;
    const int sch = (lane & 7) ^ srow8;
    const __hip_bfloat16* Agb = A + (bm + wave * 8 + srow8) * (size_t)lda + (sch << 3);
    const __hip_bfloat16* Bgb = Bt + (bn + wave * 8 + srow8) * (size_t)K + (sch << 3);
    __hip_bfloat16* AsW = As + wave * 512;
    __hip_bfloat16* BsW = Bs + wave * 512;

    auto stage = [&](int buf, int kt) {
        #pragma unroll
        for (int i = 0; i < 4; ++i)
            gl_lds16(Agb + (size_t)i * 64 * lda + kt, AsW + buf * 16384 + i * 4096);
        #pragma unroll
        for (int i = 0; i < 4; ++i)
            gl_lds16(Bgb + (size_t)i * 64 * K + kt, BsW + buf * 16384 + i * 4096);
    };

    int aoff[8], boff[4];
    #pragma unroll
    for (int mi = 0; mi < 8; ++mi) {
        int r = wm * 128 + mi * 16 + (lane & 15);
        aoff[mi] = r * 64 + (((lane >> 4) ^ (r & 7)) << 3);
    }
    #pragma unroll
    for (int ni = 0; ni < 4; ++ni) {
        int r = wn * 64 + ni * 16 + (lane & 15);
        boff[ni] = r * 64 + (((lane >> 4) ^ (r & 7)) << 3);
    }

    f32x4 acc[8][4] = {};
    const int NT = K >> 6;

    stage(0, 0);
    stage(1, 64);
    asm volatile("s_waitcnt vmcnt(8)" ::: "memory");
    __builtin_amdgcn_s_barrier();
    __builtin_amdgcn_sched_barrier(0);

    for (int t = 0; t < NT; ++t) {
        const int b = t & 1;
        const __hip_bfloat16* Ab = As + b * 16384;
        const __hip_bfloat16* Bb = Bs + b * 16384;
        bf16x8 af[8], bfr[4];

        #pragma unroll
        for (int mi = 0; mi < 8; ++mi) af[mi] = *(const bf16x8*)(Ab + aoff[mi]);
        #pragma unroll
        for (int ni = 0; ni < 4; ++ni) bfr[ni] = *(const bf16x8*)(Bb + boff[ni]);
        __builtin_amdgcn_s_setprio(1);
        #pragma unroll
        for (int mi = 0; mi < 8; ++mi)
            #pragma unroll
            for (int ni = 0; ni < 4; ++ni)
                acc[mi][ni] = MFMA16(af[mi], bfr[ni], acc[mi][ni]);
        __builtin_amdgcn_s_setprio(0);

        #pragma unroll
        for (int mi = 0; mi < 8; ++mi) af[mi] = *(const bf16x8*)(Ab + (aoff[mi] ^ 32));
        #pragma unroll
        for (int ni = 0; ni < 4; ++ni) bfr[ni] = *(const bf16x8*)(Bb + (boff[ni] ^ 32));
        __builtin_amdgcn_s_setprio(1);
        #pragma unroll
        for (int mi = 0; mi < 8; ++mi)
            #pragma unroll
            for (int ni = 0; ni < 4; ++ni)
                acc[mi][ni] = MFMA16(af[mi], bfr[ni], acc[mi][ni]);
        __builtin_amdgcn_s_setprio(0);

        __builtin_amdgcn_sched_barrier(0);
        __builtin_amdgcn_s_barrier();
        if (t + 2 < NT) {
            stage(b, (t + 2) << 6);
            asm volatile("s_waitcnt vmcnt(8)" ::: "memory");
        } else {
            asm volatile("s_waitcnt vmcnt(0)" ::: "memory");
        }
        __builtin_amdgcn_s_barrier();
        __builtin_amdgcn_sched_barrier(0);
    }

    const int row0 = (int)bm + wm * 128 + ((lane >> 4) << 2);
    const int col0 = (int)bn + wn * 64 + (lane & 15);
    #pragma unroll
    for (int mi = 0; mi < 8; ++mi)
        #pragma unroll
        for (int ni = 0; ni < 4; ++ni)
            #pragma unroll
            for (int r = 0; r < 4; ++r)
                storeC(C, (size_t)(row0 + mi * 16 + r) * N + (col0 + ni * 16), acc[mi][ni][r]);
}

// ---------------- RMSNorm in place, merged ----------------
__global__ __launch_bounds__(256)
void k_rmsnorm2(__hip_bfloat16* base, int stride,
                const float* __restrict__ w0, int D0,
                int off1, const float* __restrict__ w1, int D1) {
    const int row = blockIdx.x;
    const int which = blockIdx.y;
    const float* w = which ? w1 : w0;
    const int D = which ? D1 : D0;
    unsigned int* xr = (unsigned int*)(base + (size_t)row * stride + (which ? off1 : 0));
    const int tid = threadIdx.x;
    const int n2 = D >> 1;
    float a[3], b[3];
    float ss = 0.0f;
    int c = 0;
    for (int i = tid; i < n2; i += 256) {
        unsigned int v = xr[i];
        float lo = bfbits2f(v & 0xffffu), hi = bfbits2f(v >> 16);
        a[c] = lo; b[c] = hi; ++c;
        ss += lo * lo + hi * hi;
    }
    #pragma unroll
    for (int d = 1; d < 64; d <<= 1) ss += __shfl_xor(ss, d, 64);
    __shared__ float red[4];
    if ((tid & 63) == 0) red[tid >> 6] = ss;
    __syncthreads();
    ss = red[0] + red[1] + red[2] + red[3];
    const float rs = rsqrtf(ss / (float)D + 1e-6f);
    c = 0;
    for (int i = tid; i < n2; i += 256) {
        float lo = a[c] * rs * w[2 * i], hi = b[c] * rs * w[2 * i + 1];
        xr[i] = (unsigned int)f2bfbits(lo) | ((unsigned int)f2bfbits(hi) << 16);
        ++c;
    }
}

// ---------------- RoPE (GPT-J interleaved) in place, inline sincos, dword access ----------------
__global__ __launch_bounds__(256)
void k_rope(__hip_bfloat16* __restrict__ q, __hip_bfloat16* __restrict__ latent, int lstride,
            const int* __restrict__ positions, RopeConsts rc) {
    __shared__ float2 scs[32];
    const int s = blockIdx.x, tid = threadIdx.x;
    if (tid < 32) {
        float fr = (float)positions[s] * rc.inv_freq[tid];
        float sn, cn;
        sincosf(fr, &sn, &cn);
        scs[tid] = make_float2(cn, sn);
    }
    __syncthreads();
    #pragma unroll
    for (int p = tid; p < 1024; p += 256) {
        int head = p >> 5, i = p & 31;
        float2 c = scs[i];
        unsigned int* b = (unsigned int*)(q + (size_t)s * 6144 + head * 192 + 128 + 2 * i);
        unsigned int v = *b;
        float x1 = bfbits2f(v & 0xffffu), x2 = bfbits2f(v >> 16);
        float o1 = x1 * c.x - x2 * c.y, o2 = x2 * c.x + x1 * c.y;
        *b = (unsigned int)f2bfbits(o1) | ((unsigned int)f2bfbits(o2) << 16);
    }
    if (tid < 32) {
        float2 c = scs[tid];
        unsigned int* b = (unsigned int*)(latent + (size_t)s * lstride + 512 + 2 * tid);
        unsigned int v = *b;
        float x1 = bfbits2f(v & 0xffffu), x2 = bfbits2f(v >> 16);
        float o1 = x1 * c.x - x2 * c.y, o2 = x2 * c.x + x1 * c.y;
        *b = (unsigned int)f2bfbits(o1) | ((unsigned int)f2bfbits(o2) << 16);
    }
}

// ---------------- V transpose (wide stores): vt[h][v][t] <- kv[t][h*256+128+v] ----------------
__global__ __launch_bounds__(256)
void k_vtrans(const __hip_bfloat16* __restrict__ kv, __hip_bfloat16* __restrict__ vt) {
    __shared__ unsigned int tile[128][33];
    const int h = blockIdx.z, t0 = blockIdx.x * 128, v0 = blockIdx.y * 32;
    const int tx = threadIdx.x & 31, ty = threadIdx.x >> 5;   // tx: v, ty: t-sub
    const unsigned short* kvu = (const unsigned short*)kv;
    #pragma unroll
    for (int r = 0; r < 128; r += 8) {
        int t = t0 + r + ty;
        tile[r + ty][tx] = kvu[(size_t)t * 8192 + h * 256 + 128 + v0 + tx];
    }
    __syncthreads();
    const int vl = threadIdx.x >> 3;            // 0..31
    const int tq = (threadIdx.x & 7) << 4;      // 0,16,..,112
    unsigned short* drow = (unsigned short*)(vt + ((size_t)h * 128 + v0 + vl) * 2048 + t0 + tq);
    #pragma unroll
    for (int j4 = 0; j4 < 4; ++j4) {
        ushort4 o;
        o.x = (unsigned short)tile[tq + j4 * 4 + 0][vl];
        o.y = (unsigned short)tile[tq + j4 * 4 + 1][vl];
        o.z = (unsigned short)tile[tq + j4 * 4 + 2][vl];
        o.w = (unsigned short)tile[tq + j4 * 4 + 3][vl];
        *(ushort4*)(drow + j4 * 4) = o;
    }
}

// ---------------- Flash attention v2: 512 blocks (BQ=128 each, LPT), NBUF=1, 2 blocks/CU ----------------
// q PRE-SCALED by scale*log2(e) (exp2 domain). li per-lane partial, reduced in epilogue.
// Defer-max: skip rescale unless running max grew by > 24 (exp2 units).
// LDS 59392 B static -> 2 blocks/CU = 4 waves/SIMD; co-resident block hides the stage stall.
__global__ __launch_bounds__(512, 2)
void k_attn2(const __hip_bfloat16* __restrict__ q,      // [S][32*192] roped, pre-scaled
             const __hip_bfloat16* __restrict__ kv,     // [S][32*256]
             const __hip_bfloat16* __restrict__ latent, // [S][lstride], roped k_pe at col 512
             int lstride,
             const __hip_bfloat16* __restrict__ vt,     // [32][128][2048]
             __hip_bfloat16* __restrict__ attnout) {    // [S][32*128]
    __shared__ __hip_bfloat16 KN[8192];   // [64][128] swz
    __shared__ __hip_bfloat16 KP[4096];   // [64][64] swz
    __shared__ __hip_bfloat16 VT[8192];   // [128][64] swz
    __shared__ __hip_bfloat16 P[9216];    // 8 waves x [16][72]

    const int h = blockIdx.x & 31;
    const int qb = 15 - (int)(blockIdx.x >> 5);   // heavy q-tiles first (LPT)
    const int tid = threadIdx.x;
    const int lane = tid & 63, wave = tid >> 6;
    const int l15 = lane & 15, rquad = lane >> 4;
    const int qrw = qb * 128 + wave * 16;
    const int nt = 2 * qb + 2;

    auto stage = [&](int t0) {
        #pragma unroll
        for (int p = 0; p < 2; ++p) {
            int s = p * 512 + tid;
            int row = s >> 4, ch = s & 15;
            gl_lds16(kv + (size_t)(t0 + row) * 8192 + h * 256 + ((ch ^ (row & 7)) << 3),
                     KN + p * 4096 + wave * 512);
        }
        {
            int row = tid >> 3, ch = tid & 7;
            gl_lds16(latent + (size_t)(t0 + row) * lstride + 512 + ((ch ^ (row & 7)) << 3),
                     KP + wave * 512);
        }
        #pragma unroll
        for (int p = 0; p < 2; ++p) {
            int s = p * 512 + tid;
            int row = s >> 3, ch = s & 7;
            gl_lds16(vt + ((size_t)h * 128 + row) * 2048 + t0 + ((ch ^ (row & 7)) << 3),
                     VT + p * 4096 + wave * 512);
        }
    };

    bf16x8 qf[6];
    {
        const __hip_bfloat16* qrow = q + (size_t)(qrw + l15) * 6144 + h * 192 + (rquad << 3);
        #pragma unroll
        for (int f = 0; f < 6; ++f) qf[f] = *(const bf16x8*)(qrow + f * 32);
    }

    f32x4 o[8] = {};
    float mi_[4], li[4];
    #pragma unroll
    for (int r = 0; r < 4; ++r) { mi_[r] = -1e30f; li[r] = 0.0f; }

    for (int tt = 0; tt < nt; ++tt) {
        const int t0 = tt * 64;
        stage(t0);
        __syncthreads();                 // drains vmcnt; co-resident block computes meanwhile

        // ---- QK^T from LDS ----
        f32x4 s[4] = {};
        #pragma unroll
        for (int tb = 0; tb < 4; ++tb) {
            const int rbk = tb * 16 + l15;
            const __hip_bfloat16* knb = KN + rbk * 128;
            const __hip_bfloat16* kpb = KP + rbk * 64;
            #pragma unroll
            for (int f = 0; f < 4; ++f)
                s[tb] = MFMA16(qf[f], *(const bf16x8*)(knb + (((rquad + f * 4) ^ (rbk & 7)) << 3)), s[tb]);
            #pragma unroll
            for (int f = 0; f < 2; ++f)
                s[tb] = MFMA16(qf[4 + f], *(const bf16x8*)(kpb + (((rquad + f * 4) ^ (rbk & 7)) << 3)), s[tb]);
        }

        // ---- mask + online softmax (exp2 domain, defer-max) ----
        if (t0 + 63 > qrw) {
            const int tcol = t0 + l15;
            const int qrow0_ = qrw + (rquad << 2);
            #pragma unroll
            for (int tb = 0; tb < 4; ++tb)
                #pragma unroll
                for (int r = 0; r < 4; ++r)
                    if (tcol + tb * 16 > qrow0_ + r) s[tb][r] = -1e30f;
        }
        float pm[4];
        #pragma unroll
        for (int r = 0; r < 4; ++r) {
            float v = fmaxf(fmaxf(s[0][r], s[1][r]), fmaxf(s[2][r], s[3][r]));
            v = fmaxf(v, __shfl_xor(v, 1)); v = fmaxf(v, __shfl_xor(v, 2));
            v = fmaxf(v, __shfl_xor(v, 4)); v = fmaxf(v, __shfl_xor(v, 8));
            pm[r] = v;
        }
        bool need = (pm[0] > mi_[0] + 24.0f) || (pm[1] > mi_[1] + 24.0f) ||
                    (pm[2] > mi_[2] + 24.0f) || (pm[3] > mi_[3] + 24.0f);
        if (__any(need ? 1 : 0)) {
            float sf[4];
            #pragma unroll
            for (int r = 0; r < 4; ++r) {
                float mn = fmaxf(mi_[r], pm[r]);
                sf[r] = exp2f(mi_[r] - mn);
                mi_[r] = mn;
                li[r] *= sf[r];
            }
            #pragma unroll
            for (int vb = 0; vb < 8; ++vb)
                #pragma unroll
                for (int r = 0; r < 4; ++r) o[vb][r] *= sf[r];
        }
        #pragma unroll
        for (int tb = 0; tb < 4; ++tb)
            #pragma unroll
            for (int r = 0; r < 4; ++r) {
                float p = exp2f(s[tb][r] - mi_[r]);
                li[r] += p;
                P[wave * 1152 + ((rquad << 2) + r) * 72 + tb * 16 + l15] = __float2bfloat16(p);
            }

        // ---- PV from LDS (P wave-private) ----
        #pragma unroll
        for (int kk = 0; kk < 2; ++kk) {
            bf16x8 pf = *(const bf16x8*)&P[wave * 1152 + l15 * 72 + kk * 32 + (rquad << 3)];
            #pragma unroll
            for (int vb = 0; vb < 8; ++vb) {
                const int vrow = vb * 16 + l15;
                bf16x8 vf = *(const bf16x8*)(VT + vrow * 64 + (((rquad + kk * 4) ^ (vrow & 7)) << 3));
                o[vb] = MFMA16(pf, vf, o[vb]);
            }
        }

        __syncthreads();                 // all waves done reading before next stage overwrites
    }

    // ---- epilogue: reduce per-lane li, normalize ----
    #pragma unroll
    for (int r = 0; r < 4; ++r) {
        float v = li[r];
        v += __shfl_xor(v, 1); v += __shfl_xor(v, 2);
        v += __shfl_xor(v, 4); v += __shfl_xor(v, 8);
        const float inv = 1.0f / v;
        const int row = qrw + (rquad << 2) + r;
        __hip_bfloat16* orow = attnout + (size_t)row * 4096 + h * 128 + l15;
        #pragma unroll
        for (int vb = 0; vb < 8; ++vb) orow[vb * 16] = __float2bfloat16(o[vb][r] * inv);
    }
}

// ---------------- host ----------------
extern "C" void kernel_launch(void* const* d_in, const int* in_sizes, int n_in,
                              void* d_out, int out_size, void* d_ws, size_t ws_size,
                              hipStream_t stream) {
    const int* positions   = (const int*)d_in[0];
    const float* hidden    = (const float*)d_in[1];
    const float* w_qa      = (const float*)d_in[2];
    const float* q_a_ln_w  = (const float*)d_in[3];
    const float* w_qb      = (const float*)d_in[4];
    const float* w_kva     = (const float*)d_in[5];
    const float* kv_a_ln_w = (const float*)d_in[6];
    const float* w_kvb     = (const float*)d_in[7];
    const float* w_o       = (const float*)d_in[8];
    float* out = (float*)d_out;

    char* ws = (char*)d_ws;
    size_t off = 0;
    auto alloc = [&](size_t n) { char* p = ws + off; off += (n + 255) & ~(size_t)255; return p; };
    __hip_bfloat16* h_bf    = (__hip_bfloat16*)alloc(2048ull * 5120 * 2);
    __hip_bfloat16* wqakva  = (__hip_bfloat16*)alloc(2176ull * 5120 * 2);  // rows 0-1535 qa, 1536-2175 kva
    __hip_bfloat16* wqb_t   = (__hip_bfloat16*)alloc(6144ull * 1536 * 2);
    __hip_bfloat16* wkvb_t  = (__hip_bfloat16*)alloc(8192ull * 512 * 2);
    __hip_bfloat16* wo_t    = (__hip_bfloat16*)alloc(5120ull * 4096 * 2);
    __hip_bfloat16* qlatc   = (__hip_bfloat16*)alloc(2048ull * 2176 * 2);  // cols 0-1535 q_lat, 1536+ latent
    __hip_bfloat16* qbuf    = (__hip_bfloat16*)alloc(2048ull * 6144 * 2);
    __hip_bfloat16* kvb     = (__hip_bfloat16*)alloc(2048ull * 8192 * 2);
    __hip_bfloat16* vtb     = (__hip_bfloat16*)alloc(32ull * 128 * 2048 * 2);
    __hip_bfloat16* attnb   = (__hip_bfloat16*)alloc(2048ull * 4096 * 2);
    __hip_bfloat16* q_lat   = qlatc;
    __hip_bfloat16* latent  = qlatc + 1536;
    const int LSTR = 2176;
    (void)ws_size; (void)in_sizes; (void)n_in; (void)out_size;

    double mscale = 0.1 * log(40.0) + 1.0;
    float scale = (float)(pow(192.0, -0.5) * mscale * mscale);
    float scale2 = scale * 1.44269504088896f;   // exp2-domain: fold log2(e) into q
    RopeConsts rc;
    {
        const double PI = 3.14159265358979323846;
        double lowd = floor(64.0 * log(4096.0 / (32.0 * 2.0 * PI)) / (2.0 * log(10000.0)));
        double highd = ceil(64.0 * log(4096.0 / (1.0 * 2.0 * PI)) / (2.0 * log(10000.0)));
        if (lowd < 0.0) lowd = 0.0;
        if (highd > 63.0) highd = 63.0;
        double denom = (highd - lowd) > 0.001 ? (highd - lowd) : 0.001;
        for (int i = 0; i < 32; ++i) {
            double pf = pow(10000.0, (2.0 * i) / 64.0);
            double extra = 1.0 / pf, inter = 1.0 / (40.0 * pf);
            double ramp = ((double)i - lowd) / denom;
            ramp = ramp < 0.0 ? 0.0 : (ramp > 1.0 ? 1.0 : ramp);
            double mask = 1.0 - ramp;
            rc.inv_freq[i] = (float)(inter * (1.0 - mask) + extra * mask);
        }
    }

    bool ok256 =
        (hipFuncSetAttribute(reinterpret_cast<const void*>(k_gemm256<__hip_bfloat16>),
                             hipFuncAttributeMaxDynamicSharedMemorySize, 131072) == hipSuccess);
    bool okW2 =
        (hipFuncSetAttribute(reinterpret_cast<const void*>(k_gemm128w<2, __hip_bfloat16>),
                             hipFuncAttributeMaxDynamicSharedMemorySize, 65536) == hipSuccess);
    bool okW5 =
        (hipFuncSetAttribute(reinterpret_cast<const void*>(k_gemm128w<5, float>),
                             hipFuncAttributeMaxDynamicSharedMemorySize, 114688) == hipSuccess);
    bool okW6 =
        (hipFuncSetAttribute(reinterpret_cast<const void*>(k_gemm128w<6, __hip_bfloat16>),
                             hipFuncAttributeMaxDynamicSharedMemorySize, 131072) == hipSuccess);

    // 1. conversions + ONE batched transpose launch (5 segments)
    k_cvt_f32_bf16<<<(2048 * 5120) / 1024, 256, 0, stream>>>(hidden, h_bf, 2048L * 5120);
    {
        TransBatch tb;
        tb.src[0] = w_qa;  tb.dst[0] = wqakva;                    tb.K[0] = 5120; tb.N[0] = 1536; tb.nbx[0] = 48;
        tb.src[1] = w_kva; tb.dst[1] = wqakva + 1536ull * 5120;   tb.K[1] = 5120; tb.N[1] = 576;  tb.nbx[1] = 20;
        tb.src[2] = w_qb;  tb.dst[2] = wqb_t;                     tb.K[2] = 1536; tb.N[2] = 6144; tb.nbx[2] = 192;
        tb.src[3] = w_kvb; tb.dst[3] = wkvb_t;                    tb.K[3] = 512;  tb.N[3] = 8192; tb.nbx[3] = 256;
        tb.src[4] = w_o;   tb.dst[4] = wo_t;                      tb.K[4] = 4096; tb.N[4] = 5120; tb.nbx[4] = 160;
        int nb0 = 48 * 40, nb1 = 20 * 40, nb2 = 192 * 12, nb3 = 256 * 4, nb4 = 160 * 32;
        tb.boff[0] = 0;
        tb.boff[1] = nb0;
        tb.boff[2] = nb0 + nb1;
        tb.boff[3] = nb0 + nb1 + nb2;
        tb.boff[4] = nb0 + nb1 + nb2 + nb3;
        tb.boff[5] = nb0 + nb1 + nb2 + nb3 + nb4;
        k_transpose_batch<<<tb.boff[5], 256, 0, stream>>>(tb);
    }

    // 2. fused qa+kva projection + merged rmsnorms
    if (okW2)
        k_gemm128w<2, __hip_bfloat16><<<dim3(17, 16), 512, 65536, stream>>>(h_bf, 5120, wqakva, qlatc, 2176, 5120, 1.0f);
    else
        k_gemm128p<__hip_bfloat16><<<dim3(17, 16), 256, 0, stream>>>(h_bf, 5120, wqakva, qlatc, 2176, 5120, 1.0f);
    k_rmsnorm2<<<dim3(2048, 2), 256, 0, stream>>>(qlatc, LSTR, q_a_ln_w, 1536, 1536, kv_a_ln_w, 512);

    // 3. q path: scale*log2e folded into epilogue (exp2-domain scores)
    if (okW6)
        k_gemm128w<6, __hip_bfloat16><<<dim3(16, 16), 512, 131072, stream>>>(q_lat, LSTR, wqb_t, qbuf, 6144, 1536, scale2);
    else
        k_gemm128p<__hip_bfloat16><<<dim3(48, 16), 256, 0, stream>>>(q_lat, LSTR, wqb_t, qbuf, 6144, 1536, scale2);

    // 4. kv path (rope computes its own sincos)
    k_rope<<<2048, 256, 0, stream>>>(qbuf, latent, LSTR, positions, rc);
    if (ok256)
        k_gemm256<__hip_bfloat16><<<dim3(32, 8), 512, 131072, stream>>>(latent, LSTR, wkvb_t, kvb, 8192, 512);
    else
        k_gemm128p<__hip_bfloat16><<<dim3(64, 16), 256, 0, stream>>>(latent, LSTR, wkvb_t, kvb, 8192, 512, 1.0f);
    k_vtrans<<<dim3(16, 4, 32), 256, 0, stream>>>(kvb, vtb);

    // 5. attention v2: 512 blocks, NBUF=1 static LDS, 2 blocks/CU (occupancy hides stage stall)
    k_attn2<<<512, 512, 0, stream>>>(qbuf, kvb, latent, LSTR, vtb, attnb);

    // 6. output projection
    if (okW5)
        k_gemm128w<5, float><<<dim3(16, 16), 512, 114688, stream>>>(attnb, 4096, wo_t, out, 5120, 4096, 1.0f);
    else
        k_gemm128p<float><<<dim3(40, 16), 256, 0, stream>>>(attnb, 4096, wo_t, out, 5120, 4096, 1.0f);
}

// Round 20
// 415.921 us; speedup vs baseline: 1.0197x; 1.0197x over previous
//
#include <hip/hip_runtime.h>
#include <hip/hip_bf16.h>
#include <math.h>

#define DEVI __device__ __forceinline__

typedef __bf16 bf16x8 __attribute__((ext_vector_type(8)));
typedef float f32x4 __attribute__((ext_vector_type(4)));

#define MFMA16(a, b, c) __builtin_amdgcn_mfma_f32_16x16x32_bf16((a), (b), (c), 0, 0, 0)

struct RopeConsts { float inv_freq[32]; };

DEVI float bfbits2f(unsigned int u) { union { unsigned int i; float f; } x; x.i = u << 16; return x.f; }
DEVI unsigned short f2bfbits(float f) {
    __hip_bfloat16 h = __float2bfloat16(f);
    unsigned short u; __builtin_memcpy(&u, &h, 2); return u;
}

DEVI void gl_lds16(const __hip_bfloat16* g, __hip_bfloat16* l) {
    __builtin_amdgcn_global_load_lds((const __attribute__((address_space(1))) void*)g,
                                     (__attribute__((address_space(3))) void*)l, 16, 0, 0);
}

// ---------------- elementwise fp32 -> bf16 ----------------
__global__ void k_cvt_f32_bf16(const float* __restrict__ s, __hip_bfloat16* __restrict__ d, long n) {
    long i = ((long)blockIdx.x * 256 + threadIdx.x) * 4;
    if (i >= n) return;
    float4 f = *(const float4*)(s + i);
    ushort4 o = make_ushort4(f2bfbits(f.x), f2bfbits(f.y), f2bfbits(f.z), f2bfbits(f.w));
    *(ushort4*)((unsigned short*)d + i) = o;
}

// ---------------- batched transpose+convert (wide stores): 5 segments in one launch ----------------
struct TransBatch {
    const float* src[5];
    __hip_bfloat16* dst[5];
    int K[5], N[5], nbx[5];
    int boff[6];
};

__global__ __launch_bounds__(256)
void k_transpose_batch(TransBatch tbp) {
    __shared__ float tile[128][33];
    const int b = blockIdx.x;
    int seg = 0;
    if (b >= tbp.boff[1]) seg = 1;
    if (b >= tbp.boff[2]) seg = 2;
    if (b >= tbp.boff[3]) seg = 3;
    if (b >= tbp.boff[4]) seg = 4;
    const int local = b - tbp.boff[seg];
    const int nbx = tbp.nbx[seg];
    const int K = tbp.K[seg], N = tbp.N[seg];
    const float* __restrict__ src = tbp.src[seg];
    __hip_bfloat16* __restrict__ dst = tbp.dst[seg];
    const int nb = (local % nbx) * 32, kb = (local / nbx) * 128;

    const int tx = threadIdx.x & 31, ty = threadIdx.x >> 5;  // tx: n, ty: k-sub
    #pragma unroll
    for (int r = 0; r < 128; r += 8) {
        int k = kb + r + ty, n = nb + tx;
        tile[r + ty][tx] = (n < N) ? src[(size_t)k * N + n] : 0.0f;
    }
    __syncthreads();
    const int nl = threadIdx.x >> 3;            // 0..31
    const int kq = (threadIdx.x & 7) << 4;      // 0,16,..,112
    unsigned short* drow = (unsigned short*)(dst + (size_t)(nb + nl) * K + kb + kq);
    #pragma unroll
    for (int j4 = 0; j4 < 4; ++j4) {
        ushort4 o;
        o.x = f2bfbits(tile[kq + j4 * 4 + 0][nl]);
        o.y = f2bfbits(tile[kq + j4 * 4 + 1][nl]);
        o.z = f2bfbits(tile[kq + j4 * 4 + 2][nl]);
        o.w = f2bfbits(tile[kq + j4 * 4 + 3][nl]);
        *(ushort4*)(drow + j4 * 4) = o;
    }
}

// ---------------- C store helpers ----------------
DEVI void storeC(float* C, size_t i, float v) { C[i] = v; }
DEVI void storeC(__hip_bfloat16* C, size_t i, float v) { C[i] = __float2bfloat16(v); }

// ---------------- GEMM 128x(64*NI), 8-wave, counted-vmcnt pipeline; C scaled by alpha ----------------
template <int NI, typename CT>
__global__ __launch_bounds__(512, 2)
void k_gemm128w(const __hip_bfloat16* __restrict__ A, int lda,
                const __hip_bfloat16* __restrict__ Bt,
                CT* __restrict__ C, int N, int K, float alpha) {
    extern __shared__ __hip_bfloat16 sm[];
    __hip_bfloat16* As = sm;                    // [2][8192]
    __hip_bfloat16* Bs = sm + 16384;            // [2][NI*4096]
    const int tid = threadIdx.x;
    const int lane = tid & 63, wave = tid >> 6;
    const int wm = wave >> 2, wn = wave & 3;    // 2 x 4 wave grid
    const size_t bm = (size_t)blockIdx.y * 128, bn = (size_t)blockIdx.x * (64 * NI);

    const int srow8 = lane >> 3;
    const int sch = (lane & 7) ^ srow8;         // inverse-swizzled source chunk
    const __hip_bfloat16* Agb = A + (bm + wave * 8 + srow8) * (size_t)lda + (sch << 3);
    const __hip_bfloat16* Bgb = Bt + (bn + wave * 8 + srow8) * (size_t)K + (sch << 3);
    __hip_bfloat16* AsW = As + wave * 512;
    __hip_bfloat16* BsW = Bs + wave * 512;

    auto stage = [&](int buf, int kt) {
        #pragma unroll
        for (int i = 0; i < 2; ++i)
            gl_lds16(Agb + (size_t)i * 64 * lda + kt, AsW + buf * 8192 + i * 4096);
        #pragma unroll
        for (int i = 0; i < NI; ++i)
            gl_lds16(Bgb + (size_t)i * 64 * K + kt, BsW + buf * (NI * 4096) + i * 4096);
    };

    int aoff[4], boff[NI];
    #pragma unroll
    for (int mi = 0; mi < 4; ++mi) {
        int r = wm * 64 + mi * 16 + (lane & 15);
        aoff[mi] = r * 64 + (((lane >> 4) ^ (r & 7)) << 3);
    }
    #pragma unroll
    for (int ni = 0; ni < NI; ++ni) {
        int r = wn * (16 * NI) + ni * 16 + (lane & 15);
        boff[ni] = r * 64 + (((lane >> 4) ^ (r & 7)) << 3);
    }

    f32x4 acc[4][NI] = {};
    const int NT = K >> 6;

    stage(0, 0);
    stage(1, 64);
    asm volatile("s_waitcnt vmcnt(%0)" :: "n"(2 + NI) : "memory");
    __builtin_amdgcn_s_barrier();
    __builtin_amdgcn_sched_barrier(0);

    for (int t = 0; t < NT; ++t) {
        const int b = t & 1;
        const __hip_bfloat16* Ab = As + b * 8192;
        const __hip_bfloat16* Bb = Bs + b * (NI * 4096);
        bf16x8 af[4], bfr[NI];

        // kk = 0
        #pragma unroll
        for (int mi = 0; mi < 4; ++mi) af[mi] = *(const bf16x8*)(Ab + aoff[mi]);
        #pragma unroll
        for (int ni = 0; ni < NI; ++ni) bfr[ni] = *(const bf16x8*)(Bb + boff[ni]);
        __builtin_amdgcn_s_setprio(1);
        #pragma unroll
        for (int mi = 0; mi < 4; ++mi)
            #pragma unroll
            for (int ni = 0; ni < NI; ++ni)
                acc[mi][ni] = MFMA16(af[mi], bfr[ni], acc[mi][ni]);
        __builtin_amdgcn_s_setprio(0);

        // kk = 1
        #pragma unroll
        for (int mi = 0; mi < 4; ++mi) af[mi] = *(const bf16x8*)(Ab + (aoff[mi] ^ 32));
        #pragma unroll
        for (int ni = 0; ni < NI; ++ni) bfr[ni] = *(const bf16x8*)(Bb + (boff[ni] ^ 32));
        __builtin_amdgcn_s_setprio(1);
        #pragma unroll
        for (int mi = 0; mi < 4; ++mi)
            #pragma unroll
            for (int ni = 0; ni < NI; ++ni)
                acc[mi][ni] = MFMA16(af[mi], bfr[ni], acc[mi][ni]);
        __builtin_amdgcn_s_setprio(0);

        __builtin_amdgcn_sched_barrier(0);
        __builtin_amdgcn_s_barrier();
        if (t + 2 < NT) {
            stage(b, (t + 2) << 6);
            asm volatile("s_waitcnt vmcnt(%0)" :: "n"(2 + NI) : "memory");
        } else {
            asm volatile("s_waitcnt vmcnt(0)" ::: "memory");
        }
        __builtin_amdgcn_s_barrier();
        __builtin_amdgcn_sched_barrier(0);
    }

    const int row0 = (int)bm + wm * 64 + ((lane >> 4) << 2);
    const int col0 = (int)bn + wn * (16 * NI) + (lane & 15);
    #pragma unroll
    for (int mi = 0; mi < 4; ++mi)
        #pragma unroll
        for (int ni = 0; ni < NI; ++ni)
            #pragma unroll
            for (int r = 0; r < 4; ++r)
                storeC(C, (size_t)(row0 + mi * 16 + r) * N + (col0 + ni * 16), acc[mi][ni][r] * alpha);
}

// ---------------- GEMM 128x128, 4-wave, counted-vmcnt pipeline, 64KB static LDS ----------------
template <typename CT>
__global__ __launch_bounds__(256, 2)
void k_gemm128p(const __hip_bfloat16* __restrict__ A, int lda,
                const __hip_bfloat16* __restrict__ Bt,
                CT* __restrict__ C, int N, int K, float alpha) {
    __shared__ __hip_bfloat16 As[2 * 8192];   // [2][128][64]
    __shared__ __hip_bfloat16 Bs[2 * 8192];
    const int tid = threadIdx.x;
    const int lane = tid & 63, wave = tid >> 6;
    const int wm = wave >> 1, wn = wave & 1;           // 2 x 2 wave grid
    const size_t bm = (size_t)blockIdx.y * 128, bn = (size_t)blockIdx.x * 128;

    const int srow8 = lane >> 3;
    const int sch = (lane & 7) ^ srow8;
    const __hip_bfloat16* Agb = A + (bm + wave * 8 + srow8) * (size_t)lda + (sch << 3);
    const __hip_bfloat16* Bgb = Bt + (bn + wave * 8 + srow8) * (size_t)K + (sch << 3);
    __hip_bfloat16* AsW = As + wave * 512;
    __hip_bfloat16* BsW = Bs + wave * 512;

    auto stage = [&](int buf, int kt) {
        #pragma unroll
        for (int i = 0; i < 4; ++i)
            gl_lds16(Agb + (size_t)i * 32 * lda + kt, AsW + buf * 8192 + i * 2048);
        #pragma unroll
        for (int i = 0; i < 4; ++i)
            gl_lds16(Bgb + (size_t)i * 32 * K + kt, BsW + buf * 8192 + i * 2048);
    };

    int aoff[4], boff[4];
    #pragma unroll
    for (int mi = 0; mi < 4; ++mi) {
        int r = wm * 64 + mi * 16 + (lane & 15);
        aoff[mi] = r * 64 + (((lane >> 4) ^ (r & 7)) << 3);
    }
    #pragma unroll
    for (int ni = 0; ni < 4; ++ni) {
        int r = wn * 64 + ni * 16 + (lane & 15);
        boff[ni] = r * 64 + (((lane >> 4) ^ (r & 7)) << 3);
    }

    f32x4 acc[4][4] = {};
    const int NT = K >> 6;

    stage(0, 0);
    stage(1, 64);
    asm volatile("s_waitcnt vmcnt(8)" ::: "memory");
    __builtin_amdgcn_s_barrier();
    __builtin_amdgcn_sched_barrier(0);

    for (int t = 0; t < NT; ++t) {
        const int b = t & 1;
        const __hip_bfloat16* Ab = As + b * 8192;
        const __hip_bfloat16* Bb = Bs + b * 8192;
        bf16x8 af[4], bfr[4];

        #pragma unroll
        for (int mi = 0; mi < 4; ++mi) af[mi] = *(const bf16x8*)(Ab + aoff[mi]);
        #pragma unroll
        for (int ni = 0; ni < 4; ++ni) bfr[ni] = *(const bf16x8*)(Bb + boff[ni]);
        __builtin_amdgcn_s_setprio(1);
        #pragma unroll
        for (int mi = 0; mi < 4; ++mi)
            #pragma unroll
            for (int ni = 0; ni < 4; ++ni)
                acc[mi][ni] = MFMA16(af[mi], bfr[ni], acc[mi][ni]);
        __builtin_amdgcn_s_setprio(0);

        #pragma unroll
        for (int mi = 0; mi < 4; ++mi) af[mi] = *(const bf16x8*)(Ab + (aoff[mi] ^ 32));
        #pragma unroll
        for (int ni = 0; ni < 4; ++ni) bfr[ni] = *(const bf16x8*)(Bb + (boff[ni] ^ 32));
        __builtin_amdgcn_s_setprio(1);
        #pragma unroll
        for (int mi = 0; mi < 4; ++mi)
            #pragma unroll
            for (int ni = 0; ni < 4; ++ni)
                acc[mi][ni] = MFMA16(af[mi], bfr[ni], acc[mi][ni]);
        __builtin_amdgcn_s_setprio(0);

        __builtin_amdgcn_sched_barrier(0);
        __builtin_amdgcn_s_barrier();
        if (t + 2 < NT) {
            stage(b, (t + 2) << 6);
            asm volatile("s_waitcnt vmcnt(8)" ::: "memory");
        } else {
            asm volatile("s_waitcnt vmcnt(0)" ::: "memory");
        }
        __builtin_amdgcn_s_barrier();
        __builtin_amdgcn_sched_barrier(0);
    }

    const int row0 = (int)bm + wm * 64 + ((lane >> 4) << 2);
    const int col0 = (int)bn + wn * 64 + (lane & 15);
    #pragma unroll
    for (int mi = 0; mi < 4; ++mi)
        #pragma unroll
        for (int ni = 0; ni < 4; ++ni)
            #pragma unroll
            for (int r = 0; r < 4; ++r)
                storeC(C, (size_t)(row0 + mi * 16 + r) * N + (col0 + ni * 16), acc[mi][ni][r] * alpha);
}

// ---------------- GEMM 256x256 (8-wave, counted-vmcnt deep pipeline) ----------------
template <typename CT>
__global__ __launch_bounds__(512, 2)
void k_gemm256(const __hip_bfloat16* __restrict__ A, int lda,
               const __hip_bfloat16* __restrict__ Bt,
               CT* __restrict__ C, int N, int K) {
    extern __shared__ __hip_bfloat16 sm[];
    __hip_bfloat16* As = sm;            // [2][16384]
    __hip_bfloat16* Bs = sm + 32768;    // [2][16384]
    const int tid = threadIdx.x;
    const int lane = tid & 63, wave = tid >> 6;
    const int wm = wave >> 2, wn = wave & 3;
    const size_t bm = (size_t)blockIdx.y * 256, bn = (size_t)blockIdx.x * 256;

    const int srow8 = lane >> 3;
    const int sch = (lane & 7) ^ srow8;
    const __hip_bfloat16* Agb = A + (bm + wave * 8 + srow8) * (size_t)lda + (sch << 3);
    const __hip_bfloat16* Bgb = Bt + (bn + wave * 8 + srow8) * (size_t)K + (sch << 3);
    __hip_bfloat16* AsW = As + wave * 512;
    __hip_bfloat16* BsW = Bs + wave * 512;

    auto stage = [&](int buf, int kt) {
        #pragma unroll
        for (int i = 0; i < 4; ++i)
            gl_lds16(Agb + (size_t)i * 64 * lda + kt, AsW + buf * 16384 + i * 4096);
        #pragma unroll
        for (int i = 0; i < 4; ++i)
            gl_lds16(Bgb + (size_t)i * 64 * K + kt, BsW + buf * 16384 + i * 4096);
    };

    int aoff[8], boff[4];
    #pragma unroll
    for (int mi = 0; mi < 8; ++mi) {
        int r = wm * 128 + mi * 16 + (lane & 15);
        aoff[mi] = r * 64 + (((lane >> 4) ^ (r & 7)) << 3);
    }
    #pragma unroll
    for (int ni = 0; ni < 4; ++ni) {
        int r = wn * 64 + ni * 16 + (lane & 15);
        boff[ni] = r * 64 + (((lane >> 4) ^ (r & 7)) << 3);
    }

    f32x4 acc[8][4] = {};
    const int NT = K >> 6;

    stage(0, 0);
    stage(1, 64);
    asm volatile("s_waitcnt vmcnt(8)" ::: "memory");
    __builtin_amdgcn_s_barrier();
    __builtin_amdgcn_sched_barrier(0);

    for (int t = 0; t < NT; ++t) {
        const int b = t & 1;
        const __hip_bfloat16* Ab = As + b * 16384;
        const __hip_bfloat16* Bb = Bs + b * 16384;
        bf16x8 af[8], bfr[4];

        #pragma unroll
        for (int mi = 0; mi < 8; ++mi) af[mi] = *(const bf16x8*)(Ab + aoff[mi]);
        #pragma unroll
        for (int ni = 0; ni < 4; ++ni) bfr[ni] = *(const bf16x8*)(Bb + boff[ni]);
        __builtin_amdgcn_s_setprio(1);
        #pragma unroll
        for (int mi = 0; mi < 8; ++mi)
            #pragma unroll
            for (int ni = 0; ni < 4; ++ni)
                acc[mi][ni] = MFMA16(af[mi], bfr[ni], acc[mi][ni]);
        __builtin_amdgcn_s_setprio(0);

        #pragma unroll
        for (int mi = 0; mi < 8; ++mi) af[mi] = *(const bf16x8*)(Ab + (aoff[mi] ^ 32));
        #pragma unroll
        for (int ni = 0; ni < 4; ++ni) bfr[ni] = *(const bf16x8*)(Bb + (boff[ni] ^ 32));
        __builtin_amdgcn_s_setprio(1);
        #pragma unroll
        for (int mi = 0; mi < 8; ++mi)
            #pragma unroll
            for (int ni = 0; ni < 4; ++ni)
                acc[mi][ni] = MFMA16(af[mi], bfr[ni], acc[mi][ni]);
        __builtin_amdgcn_s_setprio(0);

        __builtin_amdgcn_sched_barrier(0);
        __builtin_amdgcn_s_barrier();
        if (t + 2 < NT) {
            stage(b, (t + 2) << 6);
            asm volatile("s_waitcnt vmcnt(8)" ::: "memory");
        } else {
            asm volatile("s_waitcnt vmcnt(0)" ::: "memory");
        }
        __builtin_amdgcn_s_barrier();
        __builtin_amdgcn_sched_barrier(0);
    }

    const int row0 = (int)bm + wm * 128 + ((lane >> 4) << 2);
    const int col0 = (int)bn + wn * 64 + (lane & 15);
    #pragma unroll
    for (int mi = 0; mi < 8; ++mi)
        #pragma unroll
        for (int ni = 0; ni < 4; ++ni)
            #pragma unroll
            for (int r = 0; r < 4; ++r)
                storeC(C, (size_t)(row0 + mi * 16 + r) * N + (col0 + ni * 16), acc[mi][ni][r]);
}

// ---------------- RMSNorm in place, merged ----------------
__global__ __launch_bounds__(256)
void k_rmsnorm2(__hip_bfloat16* base, int stride,
                const float* __restrict__ w0, int D0,
                int off1, const float* __restrict__ w1, int D1) {
    const int row = blockIdx.x;
    const int which = blockIdx.y;
    const float* w = which ? w1 : w0;
    const int D = which ? D1 : D0;
    unsigned int* xr = (unsigned int*)(base + (size_t)row * stride + (which ? off1 : 0));
    const int tid = threadIdx.x;
    const int n2 = D >> 1;
    float a[3], b[3];
    float ss = 0.0f;
    int c = 0;
    for (int i = tid; i < n2; i += 256) {
        unsigned int v = xr[i];
        float lo = bfbits2f(v & 0xffffu), hi = bfbits2f(v >> 16);
        a[c] = lo; b[c] = hi; ++c;
        ss += lo * lo + hi * hi;
    }
    #pragma unroll
    for (int d = 1; d < 64; d <<= 1) ss += __shfl_xor(ss, d, 64);
    __shared__ float red[4];
    if ((tid & 63) == 0) red[tid >> 6] = ss;
    __syncthreads();
    ss = red[0] + red[1] + red[2] + red[3];
    const float rs = rsqrtf(ss / (float)D + 1e-6f);
    c = 0;
    for (int i = tid; i < n2; i += 256) {
        float lo = a[c] * rs * w[2 * i], hi = b[c] * rs * w[2 * i + 1];
        xr[i] = (unsigned int)f2bfbits(lo) | ((unsigned int)f2bfbits(hi) << 16);
        ++c;
    }
}

// ---------------- RoPE (GPT-J interleaved) in place, inline sincos, dword access ----------------
__global__ __launch_bounds__(256)
void k_rope(__hip_bfloat16* __restrict__ q, __hip_bfloat16* __restrict__ latent, int lstride,
            const int* __restrict__ positions, RopeConsts rc) {
    __shared__ float2 scs[32];
    const int s = blockIdx.x, tid = threadIdx.x;
    if (tid < 32) {
        float fr = (float)positions[s] * rc.inv_freq[tid];
        float sn, cn;
        sincosf(fr, &sn, &cn);
        scs[tid] = make_float2(cn, sn);
    }
    __syncthreads();
    #pragma unroll
    for (int p = tid; p < 1024; p += 256) {
        int head = p >> 5, i = p & 31;
        float2 c = scs[i];
        unsigned int* b = (unsigned int*)(q + (size_t)s * 6144 + head * 192 + 128 + 2 * i);
        unsigned int v = *b;
        float x1 = bfbits2f(v & 0xffffu), x2 = bfbits2f(v >> 16);
        float o1 = x1 * c.x - x2 * c.y, o2 = x2 * c.x + x1 * c.y;
        *b = (unsigned int)f2bfbits(o1) | ((unsigned int)f2bfbits(o2) << 16);
    }
    if (tid < 32) {
        float2 c = scs[tid];
        unsigned int* b = (unsigned int*)(latent + (size_t)s * lstride + 512 + 2 * tid);
        unsigned int v = *b;
        float x1 = bfbits2f(v & 0xffffu), x2 = bfbits2f(v >> 16);
        float o1 = x1 * c.x - x2 * c.y, o2 = x2 * c.x + x1 * c.y;
        *b = (unsigned int)f2bfbits(o1) | ((unsigned int)f2bfbits(o2) << 16);
    }
}

// ---------------- V transpose (wide stores): vt[h][v][t] <- kv[t][h*256+128+v] ----------------
__global__ __launch_bounds__(256)
void k_vtrans(const __hip_bfloat16* __restrict__ kv, __hip_bfloat16* __restrict__ vt) {
    __shared__ unsigned int tile[128][33];
    const int h = blockIdx.z, t0 = blockIdx.x * 128, v0 = blockIdx.y * 32;
    const int tx = threadIdx.x & 31, ty = threadIdx.x >> 5;   // tx: v, ty: t-sub
    const unsigned short* kvu = (const unsigned short*)kv;
    #pragma unroll
    for (int r = 0; r < 128; r += 8) {
        int t = t0 + r + ty;
        tile[r + ty][tx] = kvu[(size_t)t * 8192 + h * 256 + 128 + v0 + tx];
    }
    __syncthreads();
    const int vl = threadIdx.x >> 3;            // 0..31
    const int tq = (threadIdx.x & 7) << 4;      // 0,16,..,112
    unsigned short* drow = (unsigned short*)(vt + ((size_t)h * 128 + v0 + vl) * 2048 + t0 + tq);
    #pragma unroll
    for (int j4 = 0; j4 < 4; ++j4) {
        ushort4 o;
        o.x = (unsigned short)tile[tq + j4 * 4 + 0][vl];
        o.y = (unsigned short)tile[tq + j4 * 4 + 1][vl];
        o.z = (unsigned short)tile[tq + j4 * 4 + 2][vl];
        o.w = (unsigned short)tile[tq + j4 * 4 + 3][vl];
        *(ushort4*)(drow + j4 * 4) = o;
    }
}

// ---------------- Flash attention: diagonal-paired 2xBQ128, BKV=64, 3-buf rotation ----------------
// q PRE-SCALED by scale*log2(e) (exp2 domain). li = per-lane partial, reduced in epilogue.
// Defer-max (T13): skip rescale unless the running max grew by > 24 (exp2 units; p <= 2^24).
template <int NBUF>
__global__ __launch_bounds__(512, 1)
void k_attn(const __hip_bfloat16* __restrict__ q,      // [S][32*192] roped, pre-scaled (exp2 domain)
            const __hip_bfloat16* __restrict__ kv,     // [S][32*256]
            const __hip_bfloat16* __restrict__ latent, // [S][lstride], roped k_pe at col 512
            int lstride,
            const __hip_bfloat16* __restrict__ vt,     // [32][128][2048]
            __hip_bfloat16* __restrict__ attnout) {    // [S][32*128]
    extern __shared__ __hip_bfloat16 smem[];
    __hip_bfloat16* KN = smem;                 // NBUF*8192
    __hip_bfloat16* KP = KN + NBUF * 8192;     // NBUF*4096
    __hip_bfloat16* VT = KP + NBUF * 4096;     // NBUF*8192
    __hip_bfloat16* P  = VT + NBUF * 8192;     // 8*32*72 = 18432

    const int h = blockIdx.x & 31;
    const int pr = (int)(blockIdx.x >> 5);        // 0..7; pr=0 (most tiles) first
    const int tid = threadIdx.x;
    const int lane = tid & 63, wave = tid >> 6;
    const int l15 = lane & 15, rquad = lane >> 4;
    const int qrw0 = pr * 128 + wave * 16;         // rb0 rows
    const int qrw1 = (15 - pr) * 128 + wave * 16;  // rb1 rows
    const int nt0 = 2 * pr + 2;                    // rb0 active tiles
    const int nt  = 2 * (15 - pr) + 2;             // total tiles

    auto stage = [&](int buf, int t0) {
        #pragma unroll
        for (int p = 0; p < 2; ++p) {
            int s = p * 512 + tid;
            int row = s >> 4, ch = s & 15;
            gl_lds16(kv + (size_t)(t0 + row) * 8192 + h * 256 + ((ch ^ (row & 7)) << 3),
                     KN + buf * 8192 + p * 4096 + wave * 512);
        }
        {
            int row = tid >> 3, ch = tid & 7;
            gl_lds16(latent + (size_t)(t0 + row) * lstride + 512 + ((ch ^ (row & 7)) << 3),
                     KP + buf * 4096 + wave * 512);
        }
        #pragma unroll
        for (int p = 0; p < 2; ++p) {
            int s = p * 512 + tid;
            int row = s >> 3, ch = s & 7;
            gl_lds16(vt + ((size_t)h * 128 + row) * 2048 + t0 + ((ch ^ (row & 7)) << 3),
                     VT + buf * 8192 + p * 4096 + wave * 512);
        }
    };

    bf16x8 qf[2][6];
    {
        const __hip_bfloat16* qrow0 = q + (size_t)(qrw0 + l15) * 6144 + h * 192 + (rquad << 3);
        const __hip_bfloat16* qrow1 = q + (size_t)(qrw1 + l15) * 6144 + h * 192 + (rquad << 3);
        #pragma unroll
        for (int f = 0; f < 6; ++f) {
            qf[0][f] = *(const bf16x8*)(qrow0 + f * 32);
            qf[1][f] = *(const bf16x8*)(qrow1 + f * 32);
        }
    }

    f32x4 o[2][8] = {};
    float mi_[2][4], li[2][4];   // li = per-lane partial denominator
    #pragma unroll
    for (int rb = 0; rb < 2; ++rb)
        #pragma unroll
        for (int r = 0; r < 4; ++r) { mi_[rb][r] = -1e30f; li[rb][r] = 0.0f; }

    int cur = 0;

    stage(0, 0);
    stage(1, 64);
    asm volatile("s_waitcnt vmcnt(5)" ::: "memory");   // tile 0 landed, tile 1 in flight
    __builtin_amdgcn_s_barrier();
    __builtin_amdgcn_sched_barrier(0);

    for (int tt = 0; tt < nt; ++tt) {
        const int t0 = tt * 64;
        const bool act0 = tt < nt0;    // wave-uniform
        if (NBUF == 3) cur = tt % 3;

        // 3-buf: issue next-next tile's stage at the top — hides under this tile's compute
        if (NBUF == 3 && tt + 2 < nt) stage((tt + 2) % 3, t0 + 128);

        // ---- QK^T from LDS: read each K frag once, use for active sub-blocks ----
        f32x4 s[2][4] = {};
        #pragma unroll
        for (int tb = 0; tb < 4; ++tb) {
            const int rbk = tb * 16 + l15;
            const __hip_bfloat16* knb = KN + cur * 8192 + rbk * 128;
            const __hip_bfloat16* kpb = KP + cur * 4096 + rbk * 64;
            bf16x8 kf[6];
            #pragma unroll
            for (int f = 0; f < 4; ++f)
                kf[f] = *(const bf16x8*)(knb + (((rquad + f * 4) ^ (rbk & 7)) << 3));
            #pragma unroll
            for (int f = 0; f < 2; ++f)
                kf[4 + f] = *(const bf16x8*)(kpb + (((rquad + f * 4) ^ (rbk & 7)) << 3));
            #pragma unroll
            for (int f = 0; f < 6; ++f)
                s[1][tb] = MFMA16(qf[1][f], kf[f], s[1][tb]);
            if (act0)
                #pragma unroll
                for (int f = 0; f < 6; ++f)
                    s[0][tb] = MFMA16(qf[0][f], kf[f], s[0][tb]);
        }

        // ---- mask + online softmax per active rb (exp2 domain, defer-max) ----
        #pragma unroll
        for (int rb = 0; rb < 2; ++rb) {
            if (rb == 0 && !act0) continue;
            const int qr = rb ? qrw1 : qrw0;
            if (t0 + 63 > qr) {
                const int tcol = t0 + l15;
                const int qrow0_ = qr + (rquad << 2);
                #pragma unroll
                for (int tb = 0; tb < 4; ++tb)
                    #pragma unroll
                    for (int r = 0; r < 4; ++r)
                        if (tcol + tb * 16 > qrow0_ + r) s[rb][tb][r] = -1e30f;
            }
            float pm[4];
            #pragma unroll
            for (int r = 0; r < 4; ++r) {
                float v = fmaxf(fmaxf(s[rb][0][r], s[rb][1][r]), fmaxf(s[rb][2][r], s[rb][3][r]));
                v = fmaxf(v, __shfl_xor(v, 1)); v = fmaxf(v, __shfl_xor(v, 2));
                v = fmaxf(v, __shfl_xor(v, 4)); v = fmaxf(v, __shfl_xor(v, 8));
                pm[r] = v;
            }
            // defer-max: rescale only when the running max grew past 24 (exp2 units)
            bool need = (pm[0] > mi_[rb][0] + 24.0f) || (pm[1] > mi_[rb][1] + 24.0f) ||
                        (pm[2] > mi_[rb][2] + 24.0f) || (pm[3] > mi_[rb][3] + 24.0f);
            if (__any(need ? 1 : 0)) {
                float sf[4];
                #pragma unroll
                for (int r = 0; r < 4; ++r) {
                    float mn = fmaxf(mi_[rb][r], pm[r]);
                    sf[r] = exp2f(mi_[rb][r] - mn);
                    mi_[rb][r] = mn;
                    li[rb][r] *= sf[r];
                }
                #pragma unroll
                for (int vb = 0; vb < 8; ++vb)
                    #pragma unroll
                    for (int r = 0; r < 4; ++r) o[rb][vb][r] *= sf[r];
            }

            #pragma unroll
            for (int tb = 0; tb < 4; ++tb)
                #pragma unroll
                for (int r = 0; r < 4; ++r) {
                    float p = exp2f(s[rb][tb][r] - mi_[rb][r]);
                    li[rb][r] += p;     // per-lane partial; reduced in epilogue
                    P[wave * 2304 + (rb * 16 + (rquad << 2) + r) * 72 + tb * 16 + l15] = __float2bfloat16(p);
                }
        }

        // ---- PV from LDS: read each V frag once ----
        #pragma unroll
        for (int kk = 0; kk < 2; ++kk) {
            bf16x8 pf0 = *(const bf16x8*)&P[wave * 2304 + l15 * 72 + kk * 32 + (rquad << 3)];
            bf16x8 pf1 = *(const bf16x8*)&P[wave * 2304 + (16 + l15) * 72 + kk * 32 + (rquad << 3)];
            #pragma unroll
            for (int vb = 0; vb < 8; ++vb) {
                const int vrow = vb * 16 + l15;
                bf16x8 vf = *(const bf16x8*)(VT + cur * 8192 + vrow * 64 + (((rquad + kk * 4) ^ (vrow & 7)) << 3));
                o[1][vb] = MFMA16(pf1, vf, o[1][vb]);
                if (act0) o[0][vb] = MFMA16(pf0, vf, o[0][vb]);
            }
        }

        if (NBUF == 3) {
            __builtin_amdgcn_sched_barrier(0);
            if (tt + 2 < nt) asm volatile("s_waitcnt vmcnt(5)" ::: "memory");
            else             asm volatile("s_waitcnt vmcnt(0)" ::: "memory");
            __builtin_amdgcn_s_barrier();
            __builtin_amdgcn_sched_barrier(0);
        } else {
            __builtin_amdgcn_sched_barrier(0);
            __builtin_amdgcn_s_barrier();
            if (tt + 2 < nt) {
                stage(cur, t0 + 128);
                asm volatile("s_waitcnt vmcnt(5)" ::: "memory");
            } else {
                asm volatile("s_waitcnt vmcnt(0)" ::: "memory");
            }
            __builtin_amdgcn_s_barrier();
            __builtin_amdgcn_sched_barrier(0);
            cur ^= 1;
        }
    }

    // ---- epilogue: reduce per-lane li across the 16-lane row group, then normalize ----
    #pragma unroll
    for (int rb = 0; rb < 2; ++rb)
        #pragma unroll
        for (int r = 0; r < 4; ++r) {
            float v = li[rb][r];
            v += __shfl_xor(v, 1); v += __shfl_xor(v, 2);
            v += __shfl_xor(v, 4); v += __shfl_xor(v, 8);
            const float inv = 1.0f / v;
            const int row = (rb ? qrw1 : qrw0) + (rquad << 2) + r;
            __hip_bfloat16* orow = attnout + (size_t)row * 4096 + h * 128 + l15;
            #pragma unroll
            for (int vb = 0; vb < 8; ++vb) orow[vb * 16] = __float2bfloat16(o[rb][vb][r] * inv);
        }
}

// ---------------- host ----------------
extern "C" void kernel_launch(void* const* d_in, const int* in_sizes, int n_in,
                              void* d_out, int out_size, void* d_ws, size_t ws_size,
                              hipStream_t stream) {
    const int* positions   = (const int*)d_in[0];
    const float* hidden    = (const float*)d_in[1];
    const float* w_qa      = (const float*)d_in[2];
    const float* q_a_ln_w  = (const float*)d_in[3];
    const float* w_qb      = (const float*)d_in[4];
    const float* w_kva     = (const float*)d_in[5];
    const float* kv_a_ln_w = (const float*)d_in[6];
    const float* w_kvb     = (const float*)d_in[7];
    const float* w_o       = (const float*)d_in[8];
    float* out = (float*)d_out;

    char* ws = (char*)d_ws;
    size_t off = 0;
    auto alloc = [&](size_t n) { char* p = ws + off; off += (n + 255) & ~(size_t)255; return p; };
    __hip_bfloat16* h_bf    = (__hip_bfloat16*)alloc(2048ull * 5120 * 2);
    __hip_bfloat16* wqakva  = (__hip_bfloat16*)alloc(2176ull * 5120 * 2);  // rows 0-1535 qa, 1536-2175 kva
    __hip_bfloat16* wqb_t   = (__hip_bfloat16*)alloc(6144ull * 1536 * 2);
    __hip_bfloat16* wkvb_t  = (__hip_bfloat16*)alloc(8192ull * 512 * 2);
    __hip_bfloat16* wo_t    = (__hip_bfloat16*)alloc(5120ull * 4096 * 2);
    __hip_bfloat16* qlatc   = (__hip_bfloat16*)alloc(2048ull * 2176 * 2);  // cols 0-1535 q_lat, 1536+ latent
    __hip_bfloat16* qbuf    = (__hip_bfloat16*)alloc(2048ull * 6144 * 2);
    __hip_bfloat16* kvb     = (__hip_bfloat16*)alloc(2048ull * 8192 * 2);
    __hip_bfloat16* vtb     = (__hip_bfloat16*)alloc(32ull * 128 * 2048 * 2);
    __hip_bfloat16* attnb   = (__hip_bfloat16*)alloc(2048ull * 4096 * 2);
    __hip_bfloat16* q_lat   = qlatc;
    __hip_bfloat16* latent  = qlatc + 1536;
    const int LSTR = 2176;
    (void)ws_size; (void)in_sizes; (void)n_in; (void)out_size;

    double mscale = 0.1 * log(40.0) + 1.0;
    float scale = (float)(pow(192.0, -0.5) * mscale * mscale);
    float scale2 = scale * 1.44269504088896f;   // exp2-domain: fold log2(e) into q
    RopeConsts rc;
    {
        const double PI = 3.14159265358979323846;
        double lowd = floor(64.0 * log(4096.0 / (32.0 * 2.0 * PI)) / (2.0 * log(10000.0)));
        double highd = ceil(64.0 * log(4096.0 / (1.0 * 2.0 * PI)) / (2.0 * log(10000.0)));
        if (lowd < 0.0) lowd = 0.0;
        if (highd > 63.0) highd = 63.0;
        double denom = (highd - lowd) > 0.001 ? (highd - lowd) : 0.001;
        for (int i = 0; i < 32; ++i) {
            double pf = pow(10000.0, (2.0 * i) / 64.0);
            double extra = 1.0 / pf, inter = 1.0 / (40.0 * pf);
            double ramp = ((double)i - lowd) / denom;
            ramp = ramp < 0.0 ? 0.0 : (ramp > 1.0 ? 1.0 : ramp);
            double mask = 1.0 - ramp;
            rc.inv_freq[i] = (float)(inter * (1.0 - mask) + extra * mask);
        }
    }

    bool ok256 =
        (hipFuncSetAttribute(reinterpret_cast<const void*>(k_gemm256<__hip_bfloat16>),
                             hipFuncAttributeMaxDynamicSharedMemorySize, 131072) == hipSuccess);
    bool okW2 =
        (hipFuncSetAttribute(reinterpret_cast<const void*>(k_gemm128w<2, __hip_bfloat16>),
                             hipFuncAttributeMaxDynamicSharedMemorySize, 65536) == hipSuccess);
    bool okW5 =
        (hipFuncSetAttribute(reinterpret_cast<const void*>(k_gemm128w<5, float>),
                             hipFuncAttributeMaxDynamicSharedMemorySize, 114688) == hipSuccess);
    bool okW6 =
        (hipFuncSetAttribute(reinterpret_cast<const void*>(k_gemm128w<6, __hip_bfloat16>),
                             hipFuncAttributeMaxDynamicSharedMemorySize, 131072) == hipSuccess);

    // 1. conversions + ONE batched transpose launch (5 segments)
    k_cvt_f32_bf16<<<(2048 * 5120) / 1024, 256, 0, stream>>>(hidden, h_bf, 2048L * 5120);
    {
        TransBatch tb;
        tb.src[0] = w_qa;  tb.dst[0] = wqakva;                    tb.K[0] = 5120; tb.N[0] = 1536; tb.nbx[0] = 48;
        tb.src[1] = w_kva; tb.dst[1] = wqakva + 1536ull * 5120;   tb.K[1] = 5120; tb.N[1] = 576;  tb.nbx[1] = 20;
        tb.src[2] = w_qb;  tb.dst[2] = wqb_t;                     tb.K[2] = 1536; tb.N[2] = 6144; tb.nbx[2] = 192;
        tb.src[3] = w_kvb; tb.dst[3] = wkvb_t;                    tb.K[3] = 512;  tb.N[3] = 8192; tb.nbx[3] = 256;
        tb.src[4] = w_o;   tb.dst[4] = wo_t;                      tb.K[4] = 4096; tb.N[4] = 5120; tb.nbx[4] = 160;
        int nb0 = 48 * 40, nb1 = 20 * 40, nb2 = 192 * 12, nb3 = 256 * 4, nb4 = 160 * 32;
        tb.boff[0] = 0;
        tb.boff[1] = nb0;
        tb.boff[2] = nb0 + nb1;
        tb.boff[3] = nb0 + nb1 + nb2;
        tb.boff[4] = nb0 + nb1 + nb2 + nb3;
        tb.boff[5] = nb0 + nb1 + nb2 + nb3 + nb4;
        k_transpose_batch<<<tb.boff[5], 256, 0, stream>>>(tb);
    }

    // 2. fused qa+kva projection + merged rmsnorms
    if (okW2)
        k_gemm128w<2, __hip_bfloat16><<<dim3(17, 16), 512, 65536, stream>>>(h_bf, 5120, wqakva, qlatc, 2176, 5120, 1.0f);
    else
        k_gemm128p<__hip_bfloat16><<<dim3(17, 16), 256, 0, stream>>>(h_bf, 5120, wqakva, qlatc, 2176, 5120, 1.0f);
    k_rmsnorm2<<<dim3(2048, 2), 256, 0, stream>>>(qlatc, LSTR, q_a_ln_w, 1536, 1536, kv_a_ln_w, 512);

    // 3. q path: scale*log2e folded into epilogue (exp2-domain scores)
    if (okW6)
        k_gemm128w<6, __hip_bfloat16><<<dim3(16, 16), 512, 131072, stream>>>(q_lat, LSTR, wqb_t, qbuf, 6144, 1536, scale2);
    else
        k_gemm128p<__hip_bfloat16><<<dim3(48, 16), 256, 0, stream>>>(q_lat, LSTR, wqb_t, qbuf, 6144, 1536, scale2);

    // 4. kv path (rope computes its own sincos)
    k_rope<<<2048, 256, 0, stream>>>(qbuf, latent, LSTR, positions, rc);
    if (ok256)
        k_gemm256<__hip_bfloat16><<<dim3(32, 8), 512, 131072, stream>>>(latent, LSTR, wkvb_t, kvb, 8192, 512);
    else
        k_gemm128p<__hip_bfloat16><<<dim3(64, 16), 256, 0, stream>>>(latent, LSTR, wkvb_t, kvb, 8192, 512, 1.0f);
    k_vtrans<<<dim3(16, 4, 32), 256, 0, stream>>>(kvb, vtb);

    // 5. attention: 3-buffer rotation with proven 2-buffer fallback; q pre-scaled (exp2 domain)
    {
        hipError_t fe = hipFuncSetAttribute(reinterpret_cast<const void*>(k_attn<3>),
                                            hipFuncAttributeMaxDynamicSharedMemorySize, 159744);
        if (fe == hipSuccess) {
            k_attn<3><<<256, 512, 159744, stream>>>(qbuf, kvb, latent, LSTR, vtb, attnb);
        } else {
            hipFuncSetAttribute(reinterpret_cast<const void*>(k_attn<2>),
                                hipFuncAttributeMaxDynamicSharedMemorySize, 118784);
            k_attn<2><<<256, 512, 118784, stream>>>(qbuf, kvb, latent, LSTR, vtb, attnb);
        }
    }

    // 6. output projection
    if (okW5)
        k_gemm128w<5, float><<<dim3(16, 16), 512, 114688, stream>>>(attnb, 4096, wo_t, out, 5120, 4096, 1.0f);
    else
        k_gemm128p<float><<<dim3(40, 16), 256, 0, stream>>>(attnb, 4096, wo_t, out, 5120, 4096, 1.0f);
}